// Round 17
// baseline (75.633 us; speedup 1.0000x reference)
//
#include <hip/hip_runtime.h>
#include <math.h>

// Problem constants (match reference)
#define BB   16
#define CC   64
#define LL   512
#define LP   16
#define DM   1024
#define NP   64
#define PRD  256   // period = L/2
#define HEAD 128   // PRD/2
#define NV   256   // L - PRD

typedef float f32x4 __attribute__((ext_vector_type(4)));

// ---------------------------------------------------------------------------
// Kernel A: one block per (b,c). Full pipeline (identical to R15), writes ONE
// 4KB res row to workspace.
// ---------------------------------------------------------------------------
__global__ __launch_bounds__(256) void compute_kernel(
    const float* __restrict__ dx,    const float* __restrict__ gamma,
    const float* __restrict__ beta,  const float* __restrict__ w_t,
    const float* __restrict__ b_t,   const float* __restrict__ w_s,
    const float* __restrict__ b_s,   const float* __restrict__ w_r,
    const float* __restrict__ b_r,   const float* __restrict__ w_g,
    const float* __restrict__ b_g,   float* __restrict__ resbuf)
{
    __shared__ __align__(16) float xs[LL];
    __shared__ __align__(16) float pps[LL/2 + 1];
    __shared__ __align__(16) float tvs[NV];
    __shared__ __align__(16) float pas[PRD];
    __shared__ __align__(16) float feats[48];
    __shared__ __align__(16) float sres[DM];
    __shared__ float wsum[4];
    __shared__ float wred[4];

    const int tid  = threadIdx.x;
    const int lane = tid & 63;
    const int wv   = tid >> 6;
    const int bc   = blockIdx.x;
    const int b    = bc >> 6;
    const int cown = bc & 63;

    // ---- in-block channel stats (coalesced): thread owns l = 2tid, 2tid+1.
    const float2* dxb = (const float2*)(dx + (size_t)b * CC * LL);
    float2 sv = make_float2(0.f, 0.f), qv = make_float2(0.f, 0.f);
    float2 xv = make_float2(0.f, 0.f);
#pragma unroll 8
    for (int c = 0; c < CC; ++c) {
        float2 v = dxb[c * 256 + tid];
        if (c == cown) xv = v;
        sv.x += v.x;       sv.y += v.y;
        qv.x += v.x * v.x; qv.y += v.y * v.y;
    }
    float2 mp;
    {
        float mx = sv.x * (1.0f / CC), my = sv.y * (1.0f / CC);
        float vx = (qv.x - (float)CC * mx * mx) * (1.0f / (CC - 1));
        float vy = (qv.y - (float)CC * my * my) * (1.0f / (CC - 1));
        mp.x = mx / sqrtf(vx);
        mp.y = my / sqrtf(vy);
    }

    // ---- transform (float2): x = gamma*(dx - meanp) + beta
    const size_t base = (size_t)bc * LL;
    float2 gv = ((const float2*)(gamma + base))[tid];
    float2 bv = ((const float2*)(beta  + base))[tid];
    float2 xp;
    xp.x = gv.x * (xv.x - mp.x) + bv.x;
    xp.y = gv.y * (xv.y - mp.y) + bv.y;
    ((float2*)xs)[tid] = xp;

    // ---- inclusive scan of pair-sums (256 pairs)
    float v = xp.x + xp.y;
#pragma unroll
    for (int d = 1; d < 64; d <<= 1) {
        float t = __shfl_up(v, d, 64);
        if (lane >= d) v += t;
    }
    if (lane == 63) wsum[wv] = v;
    __syncthreads();
    float off = 0.f;
    for (int w = 0; w < wv; ++w) off += wsum[w];
    pps[tid + 1] = v + off;
    if (tid == 0) pps[0] = 0.f;
    __syncthreads();

    // ---- trend via prefix sums
    const int i  = tid;
    const int k2 = i + 257;
    const float Pi = pps[i  >> 1] + ((i  & 1) ? xs[i  & ~1] : 0.f);
    const float Pk = pps[k2 >> 1] + ((k2 & 1) ? xs[k2 & ~1] : 0.f);
    const float tv = (Pk - Pi - 0.5f * (xs[i] + xs[i + 256])) * (1.0f / 256.0f);
    tvs[i] = tv;
    const float dv = xs[HEAD + i] - tv;

    // ---- mdv = mean(dv)
    float r = dv;
#pragma unroll
    for (int m = 32; m; m >>= 1) r += __shfl_xor(r, m, 64);
    if (lane == 0) wred[wv] = r;
    __syncthreads();
    const float mdv = (wred[0] + wred[1] + wred[2] + wred[3]) * (1.0f / 256.0f);

    pas[(i + 128) & 255] = dv - mdv;
    __syncthreads();

    // ---- feature dots, direct weights
    {
        const int g  = tid >> 4;
        const int ln = tid & 15;
        const f32x4* wt4  = (const f32x4*)(w_t + g * LL + HEAD);
        const f32x4* ws4a = (const f32x4*)(w_s + g * LL);
        const f32x4* ws4b = (const f32x4*)(w_s + g * LL + PRD);
        const f32x4* wr4  = (const f32x4*)(w_r + g * LL + HEAD);
        const f32x4* tv4  = (const f32x4*)tvs;
        const f32x4* pa4  = (const f32x4*)pas;
        float at = 0.f, as = 0.f, ar = 0.f;
#pragma unroll
        for (int q = 0; q < 4; ++q) {
            const int m = ln * 4 + q;
            f32x4 t  = tv4[m],  p  = pa4[m];
            f32x4 a  = wt4[m];
            f32x4 s1 = ws4a[m], s2 = ws4b[m];
            f32x4 rr = wr4[m];
            at += t.x * a.x + t.y * a.y + t.z * a.z + t.w * a.w;
            as += p.x * (s1.x + s2.x) + p.y * (s1.y + s2.y)
                + p.z * (s1.z + s2.z) + p.w * (s1.w + s2.w);
            ar += rr.x + rr.y + rr.z + rr.w;
        }
#pragma unroll
        for (int msk = 8; msk; msk >>= 1) {
            at += __shfl_xor(at, msk, 64);
            as += __shfl_xor(as, msk, 64);
            ar += __shfl_xor(ar, msk, 64);
        }
        if (ln == 0) {
            feats[g]      = at + b_t[g];
            feats[16 + g] = as + b_s[g];
            feats[32 + g] = mdv * ar + b_r[g];
        }
    }
    __syncthreads();

    // ---- matvec vs UNtransposed w_g, coalesced row-window reads (R14)
    {
        const int qsl = lane & 3;
        float fs[12];
#pragma unroll
        for (int k = 0; k < 12; ++k) fs[k] = feats[qsl * 12 + k];

        const f32x4* wg4 = (const f32x4*)w_g;
#pragma unroll 4
        for (int p = 0; p < 16; ++p) {
            const int drow = p * 64 + wv * 16 + (lane >> 2);
            const int wbase = (p * 64 + wv * 16) * 12 + 3 * lane;
            f32x4 w0 = wg4[wbase + 0];
            f32x4 w1 = wg4[wbase + 1];
            f32x4 w2 = wg4[wbase + 2];
            float acc = fs[0]*w0.x + fs[1]*w0.y + fs[2]*w0.z + fs[3]*w0.w
                      + fs[4]*w1.x + fs[5]*w1.y + fs[6]*w1.z + fs[7]*w1.w
                      + fs[8]*w2.x + fs[9]*w2.y + fs[10]*w2.z + fs[11]*w2.w;
            acc += __shfl_xor(acc, 1, 64);
            acc += __shfl_xor(acc, 2, 64);
            if (qsl == 0) sres[drow] = acc + b_g[drow];
        }
    }
    __syncthreads();

    // ---- ONE contiguous 4KB res-row write
    ((f32x4*)resbuf)[(size_t)bc * 256 + tid] = ((const f32x4*)sres)[tid];
}

// ---------------------------------------------------------------------------
// Kernel B: broadcast store with SLIDING write window. 16384 blocks; block
// k = bc*16 + j writes rows [4j, 4j+4) of bc (16 KB). 8 blocks/CU resident
// -> ~32 MB dense window sliding sequentially (fill-like), 8 generations.
// Read amplification only 16x (64 MB, LIC-served, off the HBM bus).
// ---------------------------------------------------------------------------
__global__ __launch_bounds__(256) void bcast_kernel(
    const float* __restrict__ resbuf, float* __restrict__ out)
{
    const int tid = threadIdx.x;
    const int k   = blockIdx.x;            // 0..16383
    const int bc  = k >> 4;
    const int j   = k & 15;                // 4-row group
    const f32x4 v = ((const f32x4*)resbuf)[(size_t)bc * 256 + tid];
    f32x4* op = (f32x4*)out + (size_t)bc * (NP * DM / 4)
              + (size_t)j * 4 * 256 + tid;
#pragma unroll
    for (int n = 0; n < 4; ++n)
        op[n * 256] = v;
}

// ---------------------------------------------------------------------------
extern "C" void kernel_launch(void* const* d_in, const int* in_sizes, int n_in,
                              void* d_out, int out_size, void* d_ws, size_t ws_size,
                              hipStream_t stream) {
    const float* dx    = (const float*)d_in[0];
    const float* gamma = (const float*)d_in[1];
    const float* beta  = (const float*)d_in[2];
    const float* w_t   = (const float*)d_in[3];
    const float* b_t   = (const float*)d_in[4];
    const float* w_s   = (const float*)d_in[5];
    const float* b_s   = (const float*)d_in[6];
    const float* w_r   = (const float*)d_in[7];
    const float* b_r   = (const float*)d_in[8];
    const float* w_g   = (const float*)d_in[9];
    const float* b_g   = (const float*)d_in[10];
    float* out = (float*)d_out;
    float* resbuf = (float*)d_ws;          // 1024*1024 floats (4 MB)

    compute_kernel<<<BB * CC, 256, 0, stream>>>(
        dx, gamma, beta, w_t, b_t, w_s, b_s, w_r, b_r, w_g, b_g, resbuf);
    bcast_kernel<<<BB * CC * 16, 256, 0, stream>>>(resbuf, out);
}

// Round 18
// 65.400 us; speedup vs baseline: 1.1565x; 1.1565x over previous
//
#include <hip/hip_runtime.h>
#include <math.h>

// Problem constants (match reference)
#define BB   16
#define CC   64
#define LL   512
#define LP   16
#define DM   1024
#define NP   64
#define PRD  256   // period = L/2
#define HEAD 128   // PRD/2
#define NV   256   // L - PRD

typedef float f32x4 __attribute__((ext_vector_type(4)));

// workspace layout (in floats); all offsets 16B-aligned
#define OFF_MEANP 0                       // 8192
#define OFF_WSF   8192                    // 16*256 folded seasonal weights
#define OFF_WRS   12288                   // 16 resid weight sums
#define OFF_WGT   12304                   // 48*1024 transposed w_g

// ---------------------------------------------------------------------------
// Kernel 1: blocks 0..31 = per-(b,l) channel stats; block 32 = weight folding;
// blocks 33..48 = w_g transpose ([1024][48] -> [48][1024]). (R11's prep)
// ---------------------------------------------------------------------------
__global__ __launch_bounds__(256) void statsprep_kernel(
    const float* __restrict__ dx, const float* __restrict__ w_s,
    const float* __restrict__ w_r, const float* __restrict__ w_g,
    float* __restrict__ ws)
{
    const int tid = threadIdx.x, bid = blockIdx.x;
    if (bid < 32) {
        int id = bid * 256 + tid;            // 0..8191
        int b = id >> 9, l = id & 511;
        const float* p = dx + (size_t)b * CC * LL + l;
        float s = 0.f, sq = 0.f;
#pragma unroll 8
        for (int c = 0; c < CC; ++c) {
            float v = p[(size_t)c * LL];
            s += v; sq += v * v;
        }
        float mean = s * (1.0f / CC);
        float var  = (sq - (float)CC * mean * mean) * (1.0f / (CC - 1));
        ws[OFF_MEANP + id] = mean / sqrtf(var);
    } else if (bid == 32) {
        // fold seasonal weights: wsf[g][m] = w_s[g][m] + w_s[g][m+256]
#pragma unroll
        for (int idx = tid; idx < 16 * PRD; idx += 256) {
            int g = idx >> 8, m = idx & 255;
            ws[OFF_WSF + idx] = w_s[g * LL + m] + w_s[g * LL + PRD + m];
        }
        // resid weight sums: wrs[g] = sum w_r[g][128:384]
        int g = tid >> 4, ln = tid & 15;
        float s = 0.f;
        for (int k = ln; k < PRD; k += 16) s += w_r[g * LL + HEAD + k];
#pragma unroll
        for (int m = 8; m; m >>= 1) s += __shfl_xor(s, m, 16);
        if (ln == 0) ws[OFF_WRS + g] = s;
    } else {
        // transpose w_g: wgt[j*1024 + d] = w_g[d*48 + j]
        int base = (bid - 33) * 3072 + tid;
#pragma unroll
        for (int k = 0; k < 12; ++k) {
            int e = base + k * 256;          // e = j*1024 + d
            int j = e >> 10, d = e & 1023;
            ws[OFF_WGT + e] = w_g[d * 48 + j];
        }
    }
}

// ---------------------------------------------------------------------------
// Kernel 2 (fused): one block per (b,c). Transform (meanp from prep) -> scan
// decompose -> 48 features (folded weights) -> f32x4 matvec vs w_gT (48
// coalesced 1KB loads, acc in registers) -> DIRECT broadcast stores.
// No sres staging, no final barrier: waves drift, store/compute overlap.
// ---------------------------------------------------------------------------
__global__ __launch_bounds__(256) void fused_kernel(
    const float* __restrict__ dx,    const float* __restrict__ gamma,
    const float* __restrict__ beta,  const float* __restrict__ w_t,
    const float* __restrict__ b_t,   const float* __restrict__ b_s,
    const float* __restrict__ b_r,   const float* __restrict__ b_g,
    const float* __restrict__ ws,    float* __restrict__ out)
{
    __shared__ __align__(16) float xs[LL];
    __shared__ __align__(16) float pps[LL/2 + 1];
    __shared__ __align__(16) float tvs[NV];
    __shared__ __align__(16) float pas[PRD];
    __shared__ __align__(16) float feats[48];
    __shared__ float wsum[4];
    __shared__ float wred[4];

    const int tid  = threadIdx.x;
    const int lane = tid & 63;
    const int wv   = tid >> 6;
    const int bc   = blockIdx.x;
    const int b    = bc >> 6;

    // ---- transform (float2): x = gamma*(dx - meanp) + beta
    const size_t base = (size_t)bc * LL;
    float2 xv = ((const float2*)(dx    + base))[tid];
    float2 gv = ((const float2*)(gamma + base))[tid];
    float2 bv = ((const float2*)(beta  + base))[tid];
    float2 mv = ((const float2*)(ws + OFF_MEANP + (size_t)b * LL))[tid];
    float2 xp;
    xp.x = gv.x * (xv.x - mv.x) + bv.x;
    xp.y = gv.y * (xv.y - mv.y) + bv.y;
    ((float2*)xs)[tid] = xp;

    // ---- inclusive scan of pair-sums (256 pairs)
    float v = xp.x + xp.y;
#pragma unroll
    for (int d = 1; d < 64; d <<= 1) {
        float t = __shfl_up(v, d, 64);
        if (lane >= d) v += t;
    }
    if (lane == 63) wsum[wv] = v;
    __syncthreads();
    float off = 0.f;
    for (int w = 0; w < wv; ++w) off += wsum[w];
    pps[tid + 1] = v + off;
    if (tid == 0) pps[0] = 0.f;
    __syncthreads();

    // ---- trend via prefix sums
    const int i  = tid;
    const int k2 = i + 257;
    const float Pi = pps[i  >> 1] + ((i  & 1) ? xs[i  & ~1] : 0.f);
    const float Pk = pps[k2 >> 1] + ((k2 & 1) ? xs[k2 & ~1] : 0.f);
    const float tv = (Pk - Pi - 0.5f * (xs[i] + xs[i + 256])) * (1.0f / 256.0f);
    tvs[i] = tv;
    const float dv = xs[HEAD + i] - tv;

    // ---- mdv = mean(dv)
    float r = dv;
#pragma unroll
    for (int m = 32; m; m >>= 1) r += __shfl_xor(r, m, 64);
    if (lane == 0) wred[wv] = r;
    __syncthreads();
    const float mdv = (wred[0] + wred[1] + wred[2] + wred[3]) * (1.0f / 256.0f);

    pas[(i + 128) & 255] = dv - mdv;
    __syncthreads();

    // ---- feature dots with folded weights (8 float4 loads/thread)
    {
        const int g  = tid >> 4;
        const int ln = tid & 15;
        const f32x4* wt4  = (const f32x4*)(w_t + g * LL + HEAD);
        const f32x4* wsf4 = (const f32x4*)(ws + OFF_WSF + g * PRD);
        const f32x4* tv4  = (const f32x4*)tvs;
        const f32x4* pa4  = (const f32x4*)pas;
        float at = 0.f, as = 0.f;
#pragma unroll
        for (int q = 0; q < 4; ++q) {
            const int m = ln * 4 + q;
            f32x4 t = tv4[m], p = pa4[m];
            f32x4 a = wt4[m], sfw = wsf4[m];
            at += t.x * a.x + t.y * a.y + t.z * a.z + t.w * a.w;
            as += p.x * sfw.x + p.y * sfw.y + p.z * sfw.z + p.w * sfw.w;
        }
#pragma unroll
        for (int msk = 8; msk; msk >>= 1) {
            at += __shfl_xor(at, msk, 64);
            as += __shfl_xor(as, msk, 64);
        }
        if (ln == 0) {
            feats[g]      = at + b_t[g];
            feats[16 + g] = as + b_s[g];
            feats[32 + g] = mdv * ws[OFF_WRS + g] + b_r[g];
        }
    }
    __syncthreads();

    // ---- f32x4 matvec: thread owns d = 4*tid..4*tid+3 (48 coalesced 1KB
    // wave-loads from L2-hot w_gT); acc stays in registers.
    const f32x4* wT4 = (const f32x4*)(ws + OFF_WGT);
    f32x4 acc = ((const f32x4*)b_g)[tid];
#pragma unroll
    for (int j = 0; j < 48; ++j)
        acc += feats[j] * wT4[j * 256 + tid];

    // ---- direct broadcast stores, NO barrier (waves drift & overlap)
    f32x4* op = (f32x4*)out + (size_t)bc * (NP * DM / 4) + tid;
#pragma unroll
    for (int n = 0; n < NP; ++n)
        op[(size_t)n * (DM / 4)] = acc;
}

// ---------------------------------------------------------------------------
extern "C" void kernel_launch(void* const* d_in, const int* in_sizes, int n_in,
                              void* d_out, int out_size, void* d_ws, size_t ws_size,
                              hipStream_t stream) {
    const float* dx    = (const float*)d_in[0];
    const float* gamma = (const float*)d_in[1];
    const float* beta  = (const float*)d_in[2];
    const float* w_t   = (const float*)d_in[3];
    const float* b_t   = (const float*)d_in[4];
    const float* w_s   = (const float*)d_in[5];
    const float* b_s   = (const float*)d_in[6];
    const float* w_r   = (const float*)d_in[7];
    const float* b_r   = (const float*)d_in[8];
    const float* w_g   = (const float*)d_in[9];
    const float* b_g   = (const float*)d_in[10];
    float* out = (float*)d_out;
    float* ws  = (float*)d_ws;

    statsprep_kernel<<<49, 256, 0, stream>>>(dx, w_s, w_r, w_g, ws);
    fused_kernel<<<BB * CC, 256, 0, stream>>>(
        dx, gamma, beta, w_t, b_t, b_s, b_r, b_g, ws, out);
}